// Round 13
// baseline (279.889 us; speedup 1.0000x reference)
//
#include <hip/hip_runtime.h>
#include <math.h>

#define EPS 1e-5f

typedef _Float16 half8 __attribute__((ext_vector_type(8)));
typedef float f32x4 __attribute__((ext_vector_type(4)));

// H/L global layout per row: [tile(8)][chunk(8)][col(64)] x 8 halves (16B units).

// bq in [0,96): b = bq/12, t = bq%12; x1seq row = b*12 + min(t+1, 11)
__device__ __forceinline__ int src_row(int bq) {
    int b = bq / 12, t = bq - b * 12;
    int t2 = (t + 1 < 12) ? (t + 1) : 11;
    return b * 12 + t2;
}

// ---------------- erase0: y0 = BN(W_e @ mean_n(x) + b_e); bias0 = W2_0 @ y0 ----------------
__global__ __launch_bounds__(256) void erase0_kernel(
    const float* __restrict__ x, const float* __restrict__ w0,
    const float* __restrict__ w_e, const float* __restrict__ b_e,
    const float* __restrict__ g_e, const float* __restrict__ be_e,
    const float* __restrict__ m_e, const float* __restrict__ v_e,
    float* __restrict__ bias0)
{
    __shared__ float part[256];
    __shared__ float res[64];
    __shared__ float sy[64];
    int bq = blockIdx.x, tid = threadIdx.x;
    int c = tid >> 2, p = tid & 3;
    const float* xb = x + (size_t)bq * 32768 + c * 512 + p * 128;
    float acc = 0.f;
    for (int ii = 0; ii < 128; ii += 4) {
        float4 v = *(const float4*)(xb + ii);
        acc += v.x + v.y + v.z + v.w;
    }
    part[tid] = acc;
    __syncthreads();
    if (p == 0) res[c] = (part[tid] + part[tid+1] + part[tid+2] + part[tid+3]) * (1.f/512.f);
    __syncthreads();
    if (tid < 64) {
        float a = b_e[tid];
        for (int cc = 0; cc < 64; ++cc) a += w_e[tid*64+cc] * res[cc];
        float s = g_e[tid] / sqrtf(v_e[tid] + EPS);
        sy[tid] = (a - m_e[tid]) * s + be_e[tid];
    }
    __syncthreads();
    if (tid < 64) {
        float a = 0.f;
        for (int cc = 0; cc < 64; ++cc) a += w0[tid * 128 + 64 + cc] * sy[cc];
        bias0[bq * 64 + tid] = a;
    }
}

// ---------------- prep: fp16 split of raw x (chunk layout) + colnorms + W' splits ----------------
// grid = 768. blockIdx = ct*96 + bq (XCD swizzle).
__global__ __launch_bounds__(256) void prep_kernel(
    const float* __restrict__ X,
    _Float16* __restrict__ H, _Float16* __restrict__ L, float* __restrict__ xn,
    const float* __restrict__ w0, const float* __restrict__ w1,
    _Float16* __restrict__ wh0, _Float16* __restrict__ wl0,
    _Float16* __restrict__ wh1, _Float16* __restrict__ wl1)
{
    __shared__ float lds[64 * 65];
    __shared__ float xnp[4 * 64];
    int raw = blockIdx.x;
    int bq = raw % 96;
    int ct = raw / 96;
    const float* Xb = X + (size_t)bq * 32768 + ct * 64;
    int tid = threadIdx.x;
    for (int p = 0; p < 16; ++p) {
        int t = p * 256 + tid;
        int c = t >> 6, col = t & 63;
        lds[c * 65 + col] = Xb[c * 512 + col];
    }
    __syncthreads();
    int col = tid & 63, g = tid >> 6;
    half8 hv[2], lv[2];
    float s = 0.f;
    #pragma unroll
    for (int k = 0; k < 16; ++k) {
        int c = g * 16 + k;
        float v = lds[c * 65 + col];
        _Float16 h = (_Float16)v;
        _Float16 lo = (_Float16)(v - (float)h);
        hv[k >> 3][k & 7] = h;
        lv[k >> 3][k & 7] = lo;
        s += v * v;
    }
    size_t obase = (size_t)bq * 32768 + ((size_t)(ct * 8 + 2 * g) * 64 + col) * 8;
    *(half8*)(H + obase) = hv[0];
    *(half8*)(H + obase + 512) = hv[1];
    *(half8*)(L + obase) = lv[0];
    *(half8*)(L + obase + 512) = lv[1];
    xnp[g * 64 + col] = s;
    __syncthreads();
    if (tid < 64)
        xn[bq * 512 + ct * 64 + tid] =
            xnp[tid] + xnp[64 + tid] + xnp[128 + tid] + xnp[192 + tid];
    if (raw < 2) {
        const float* W = raw ? w1 : w0;
        _Float16* WH = raw ? wh1 : wh0;
        _Float16* WL = raw ? wl1 : wl0;
        for (int t = tid; t < 8192; t += 256) {
            int o = t >> 6, c = t & 63;
            float v = (o < 64) ? W[o * 128 + c]
                               : (W[(o - 64) * 128 + 64 + c] - W[(o - 64) * 128 + c]);
            _Float16 h = (_Float16)v;
            WH[t] = h;
            WL[t] = (_Float16)(v - (float)h);
        }
    }
}

// ---------------- kNN v6: mask folded into the score epilogue, plain staging ----------------
// score' = m_j ? fma(2*m_i, dot, -xn_j) : +0.0  — bit-identical selections to the
// staged-zero version (R10-R12) but with the unmasked kernel's register footprint.
// Prefetch issued AFTER the score phase so its 16 regs are live only through the sort.
template<int MASKED>
__global__ __launch_bounds__(256, 5) void knn_kernel(
    const _Float16* __restrict__ H, const _Float16* __restrict__ L,
    const float* __restrict__ xn, const float* __restrict__ masks, int remap,
    int* __restrict__ idx_out, int K)
{
    __shared__ float4 jbufH4[512];
    __shared__ float4 jbufL4[512];
    __shared__ float smask[MASKED ? 512 : 4];
    __shared__ unsigned ldsMV[4][64 * 11];
    __shared__ unsigned short ldsMJ[4][64 * 11];
    int raw = blockIdx.x;
    int bq = raw % 96;
    int itile = raw / 96;
    int row = remap ? src_row(bq) : bq;
    int tid = threadIdx.x, w = tid >> 6, l = tid & 63;
    int lane16 = l & 15, quad = l >> 4;
    const size_t base = (size_t)row * 32768;
    const _Float16* Hb = H + base;
    const _Float16* Lb = L + base;
    if (MASKED) {
        smask[tid] = masks[bq * 512 + tid];
        smask[tid + 256] = masks[bq * 512 + tid + 256];
    }
    int irow = itile * 64 + w * 16 + lane16;
    size_t bo = ((size_t)(itile * 8 + quad) * 64 + (w * 16 + lane16)) * 8;
    half8 Bh0 = *(const half8*)(Hb + bo);
    half8 Bh1 = *(const half8*)(Hb + bo + 2048);
    half8 Bl0 = *(const half8*)(Lb + bo);
    half8 Bl1 = *(const half8*)(Lb + bo + 2048);
    float mi2 = 2.f;
    if (MASKED) mi2 = 2.f * masks[bq * 512 + irow];

    unsigned kv[10]; int kj[10];
    #pragma unroll
    for (int qq = 0; qq < 10; ++qq) { kv[qq] = 0u; kj[qq] = 0; }

    auto casu = [](unsigned& a, unsigned& b) {
        unsigned mn = a < b ? a : b;
        unsigned mx = a < b ? b : a;
        a = mn; b = mx;
    };
    auto cas_kj = [](unsigned& ka, int& ja, unsigned& kb, int& jb2) {
        bool sw = ka > kb;
        unsigned tk = ka; int tj = ja;
        ka = sw ? kb : ka; ja = sw ? jb2 : ja;
        kb = sw ? tk : kb; jb2 = sw ? tj : jb2;
    };

    const float* xnb = xn + row * 512;
    const _Float16* jH = (const _Float16*)jbufH4;
    const _Float16* jL = (const _Float16*)jbufL4;
    float4 pa0, pa1, pb0, pb1;
    {
        const float4* gh = (const float4*)(Hb);
        const float4* gl = (const float4*)(Lb);
        pa0 = gh[tid]; pa1 = gh[256 + tid];
        pb0 = gl[tid]; pb1 = gl[256 + tid];
    }
    for (int jt = 0; jt < 8; ++jt) {
        if (jt) __syncthreads();           // prev compute done reading jbuf
        jbufH4[tid] = pa0; jbufH4[256 + tid] = pa1;
        jbufL4[tid] = pb0; jbufL4[256 + tid] = pb1;
        __syncthreads();                   // tile staged (also covers smask at jt=0)
        unsigned d[16];
        #pragma unroll
        for (int g = 0; g < 4; ++g) {
            int u = quad * 64 + g * 16 + lane16;
            half8 Ah0 = *(const half8*)(jH + (size_t)u * 8);
            half8 Ah1 = *(const half8*)(jH + (size_t)u * 8 + 2048);
            half8 Al0 = *(const half8*)(jL + (size_t)u * 8);
            half8 Al1 = *(const half8*)(jL + (size_t)u * 8 + 2048);
            f32x4 acc = {0.f, 0.f, 0.f, 0.f};
            acc = __builtin_amdgcn_mfma_f32_16x16x32_f16(Ah0, Bh0, acc, 0, 0, 0);
            acc = __builtin_amdgcn_mfma_f32_16x16x32_f16(Ah1, Bh1, acc, 0, 0, 0);
            acc = __builtin_amdgcn_mfma_f32_16x16x32_f16(Al0, Bh0, acc, 0, 0, 0);
            acc = __builtin_amdgcn_mfma_f32_16x16x32_f16(Al1, Bh1, acc, 0, 0, 0);
            acc = __builtin_amdgcn_mfma_f32_16x16x32_f16(Ah0, Bl0, acc, 0, 0, 0);
            acc = __builtin_amdgcn_mfma_f32_16x16x32_f16(Ah1, Bl1, acc, 0, 0, 0);
            int jb = jt * 64 + g * 16 + quad * 4;
            float4 xn4 = *(const float4*)&xnb[jb];
            float4 mj4;
            if (MASKED) mj4 = *(const float4*)&smask[jb];
            #pragma unroll
            for (int r = 0; r < 4; ++r) {
                float xnr = (r == 0 ? xn4.x : r == 1 ? xn4.y : r == 2 ? xn4.z : xn4.w);
                float sc = fmaf(mi2, acc[r], -xnr);
                if (MASKED) {
                    float mjr = (r == 0 ? mj4.x : r == 1 ? mj4.y : r == 2 ? mj4.z : mj4.w);
                    sc = (mjr != 0.f) ? sc : 0.0f;   // select keeps +0.0 tie class exact
                }
                int bi = __float_as_int(sc);
                unsigned u2 = (unsigned)(bi ^ ((bi >> 31) | 0x80000000));
                int slot = g * 4 + r;
                d[slot] = (u2 & 0xFFFFFFF0u) | (unsigned)(15 - slot);
            }
        }
        if (jt < 7) {                      // prefetch AFTER scores: regs live only over sort
            const float4* gh = (const float4*)(Hb + (jt + 1) * 4096);
            const float4* gl = (const float4*)(Lb + (jt + 1) * 4096);
            pa0 = gh[tid]; pa1 = gh[256 + tid];
            pb0 = gl[tid]; pb1 = gl[256 + tid];
        }
        // Batcher odd-even mergesort-16 ascending, value-only (2-inst CAS)
        #pragma unroll
        for (int p = 1; p < 16; p <<= 1) {
            #pragma unroll
            for (int k = p; k >= 1; k >>= 1) {
                #pragma unroll
                for (int j = k & (p - 1); j + k < 16; j += 2 * k) {
                    #pragma unroll
                    for (int i = 0; i < k; ++i) {
                        if ((i + j + k < 16) &&
                            ((i + j) / (2 * p) == (i + j + k) / (2 * p)))
                            casu(d[i + j], d[i + j + k]);
                    }
                }
            }
        }
        // top-10 of union: pair kv[i] (asc) with d[15-i], decode j for taken
        #pragma unroll
        for (int i = 0; i < 10; ++i) {
            unsigned dv = d[15 - i];
            int code = 15 - (int)(dv & 15u);
            int jnew = jt * 64 + (code >> 2) * 16 + quad * 4 + (code & 3);
            bool keep = kv[i] >= dv;
            kj[i] = keep ? kj[i] : jnew;
            kv[i] = keep ? kv[i] : dv;
        }
        // bitonic clean length-10
        cas_kj(kv[0], kj[0], kv[8], kj[8]);
        cas_kj(kv[1], kj[1], kv[9], kj[9]);
        cas_kj(kv[0], kj[0], kv[4], kj[4]);
        cas_kj(kv[1], kj[1], kv[5], kj[5]);
        cas_kj(kv[2], kj[2], kv[6], kj[6]);
        cas_kj(kv[3], kj[3], kv[7], kj[7]);
        cas_kj(kv[0], kj[0], kv[2], kj[2]);
        cas_kj(kv[1], kj[1], kv[3], kj[3]);
        cas_kj(kv[4], kj[4], kv[6], kj[6]);
        cas_kj(kv[5], kj[5], kv[7], kj[7]);
        cas_kj(kv[0], kj[0], kv[1], kj[1]);
        cas_kj(kv[2], kj[2], kv[3], kj[3]);
        cas_kj(kv[4], kj[4], kv[5], kj[5]);
        cas_kj(kv[6], kj[6], kv[7], kj[7]);
        cas_kj(kv[8], kj[8], kv[9], kj[9]);
    }
    #pragma unroll
    for (int qq = 0; qq < 10; ++qq) {
        ldsMV[w][(lane16 * 4 + quad) * 11 + qq] = kv[qq];
        ldsMJ[w][(lane16 * 4 + quad) * 11 + qq] = (unsigned short)kj[qq];
    }
    __syncthreads();
    if (quad == 0) {
        const unsigned* MV = &ldsMV[w][lane16 * 44];
        const unsigned short* MJ = &ldsMJ[w][lane16 * 44];
        int p0 = 9, p1 = 9, p2 = 9, p3 = 9;
        int* op = idx_out + ((size_t)bq * 512 + irow) * 16;
        for (int t = 0; t < K; ++t) {
            unsigned bv = 0u; int bj = 0x7fffffff; int bc = -1;
            { unsigned v = MV[p0]; int j = MJ[p0];
              if (v > bv || (v == bv && j < bj)) { bv = v; bj = j; bc = 0; } }
            { unsigned v = MV[11 + p1]; int j = MJ[11 + p1];
              if (v > bv || (v == bv && j < bj)) { bv = v; bj = j; bc = 1; } }
            { unsigned v = MV[22 + p2]; int j = MJ[22 + p2];
              if (v > bv || (v == bv && j < bj)) { bv = v; bj = j; bc = 2; } }
            { unsigned v = MV[33 + p3]; int j = MJ[33 + p3];
              if (v > bv || (v == bv && j < bj)) { bv = v; bj = j; bc = 3; } }
            if (bc == 0) --p0; else if (bc == 1) --p1; else if (bc == 2) --p2; else --p3;
            op[t] = bj;
        }
    }
}

// ---------------- fused branch v3: grid (96,8), 8 o's per block, LDS 44 KB -> 3 blocks/CU ----
template<int ACC>
__global__ void __attribute__((amdgpu_flat_work_group_size(256, 256), amdgpu_waves_per_eu(2, 4)))
fused_branch_kernel(
    const _Float16* __restrict__ H, const _Float16* __restrict__ L,
    const _Float16* __restrict__ WH, const _Float16* __restrict__ WL,
    const int* __restrict__ idx, const float* __restrict__ masks, int remap,
    const float* __restrict__ bias,
    const float* __restrict__ g, const float* __restrict__ bb,
    const float* __restrict__ mm, const float* __restrict__ vv,
    float* __restrict__ out_p, float* __restrict__ vec_out)
{
    __shared__ float ldsA[8 * 512];            // 16 KB
    __shared__ float ldsB[8 * 512];            // 16 KB
    __shared__ unsigned short ldsIdx[512 * 10]; // 10 KB
    __shared__ float smask[512];               // 2 KB
    int bq = blockIdx.x, ob = blockIdx.y * 8;
    int row = remap ? src_row(bq) : bq;
    bool use_mask = (masks != nullptr);
    int tid = threadIdx.x, w = tid >> 6, l = tid & 63;
    int lane16 = l & 15, quad = l >> 4;
    const size_t base = (size_t)row * 32768;
    for (int p = 0; p < 20; ++p) {
        int t = p * 256 + tid;
        int i = t / 10, q = t - i * 10;
        ldsIdx[t] = (unsigned short)idx[((size_t)bq * 512 + i) * 16 + q];
    }
    if (use_mask) {
        smask[tid] = masks[bq * 512 + tid];
        smask[tid + 256] = masks[bq * 512 + tid + 256];
    }
    __syncthreads();
    {
        int wrow = (lane16 < 8) ? (ob + lane16) : (64 + ob + (lane16 - 8));
        size_t woff = (size_t)wrow * 64 + quad * 8;
        half8 Ah0 = *(const half8*)(WH + woff);
        half8 Ah1 = *(const half8*)(WH + woff + 32);
        half8 Al0 = *(const half8*)(WL + woff);
        half8 Al1 = *(const half8*)(WL + woff + 32);
        float* dst = (quad < 2) ? (ldsA + (quad * 4) * 512) : (ldsB + ((quad - 2) * 4) * 512);
        for (int k = 0; k < 8; ++k) {
            int it = w * 8 + k;
            size_t off = base + (((size_t)(it >> 2) * 8 + quad) * 64 + (it & 3) * 16 + lane16) * 8;
            half8 Xh0 = *(const half8*)(H + off);
            half8 Xh1 = *(const half8*)(H + off + 2048);
            half8 Xl0 = *(const half8*)(L + off);
            half8 Xl1 = *(const half8*)(L + off + 2048);
            if (use_mask) {
                float m = smask[it * 16 + lane16];
                if (m == 0.f) {
                    half8 z = {};
                    Xh0 = z; Xh1 = z; Xl0 = z; Xl1 = z;
                }
            }
            f32x4 acc = {0.f, 0.f, 0.f, 0.f};
            acc = __builtin_amdgcn_mfma_f32_16x16x32_f16(Ah0, Xh0, acc, 0, 0, 0);
            acc = __builtin_amdgcn_mfma_f32_16x16x32_f16(Ah1, Xh1, acc, 0, 0, 0);
            acc = __builtin_amdgcn_mfma_f32_16x16x32_f16(Ah0, Xl0, acc, 0, 0, 0);
            acc = __builtin_amdgcn_mfma_f32_16x16x32_f16(Ah1, Xl1, acc, 0, 0, 0);
            acc = __builtin_amdgcn_mfma_f32_16x16x32_f16(Al0, Xh0, acc, 0, 0, 0);
            acc = __builtin_amdgcn_mfma_f32_16x16x32_f16(Al1, Xh1, acc, 0, 0, 0);
            #pragma unroll
            for (int r = 0; r < 4; ++r)
                dst[r * 512 + it * 16 + lane16] = acc[r];
        }
    }
    __syncthreads();
    float ssr[2], str[2];
    #pragma unroll
    for (int oo = 0; oo < 2; ++oo) {
        int o = ob + w * 2 + oo;
        float sc = g[o] / sqrtf(vv[o] + EPS);
        ssr[oo] = sc;
        str[oo] = bb[o] - mm[o] * sc + bias[bq * 64 + o] * sc;
    }
    float omax[2], osum[2];
    #pragma unroll
    for (int oo = 0; oo < 2; ++oo) { omax[oo] = -3.4e38f; osum[oo] = 0.f; }
    const float* Aw = ldsA + (w * 2) * 512;
    const float* Bw = ldsB + (w * 2) * 512;
    for (int s = 0; s < 8; ++s) {
        int i = l + 64 * s;
        int idr[10];
        const unsigned short* ip = &ldsIdx[i * 10];
        #pragma unroll
        for (int q = 0; q < 10; ++q) idr[q] = ip[q];
        #pragma unroll
        for (int oo = 0; oo < 2; ++oo) {
            const float* Ao = Aw + oo * 512;
            float mx = Ao[idr[0]];
            #pragma unroll
            for (int q = 1; q < 10; ++q) mx = fmaxf(mx, Ao[idr[q]]);
            float val = (mx + Bw[oo * 512 + i]) * ssr[oo] + str[oo];
            float y = val > 0.f ? val : 0.2f * val;
            omax[oo] = fmaxf(omax[oo], y);
            osum[oo] += y;
        }
    }
    #pragma unroll
    for (int oo = 0; oo < 2; ++oo) {
        float M = omax[oo], S = osum[oo];
        #pragma unroll
        for (int off = 32; off >= 1; off >>= 1) {
            M = fmaxf(M, __shfl_down(M, off));
            S += __shfl_down(S, off);
        }
        if (l == 0) {
            int o = ob + w * 2 + oo;
            float* po = out_p + bq * 128;
            if (ACC) {
                po[o] += M;
                po[64 + o] += S * (1.f / 512.f);
            } else {
                po[o] = M;
                po[64 + o] = S * (1.f / 512.f);
                vec_out[bq * 64 + o] = M;
            }
        }
    }
}

// ---------------- corre_binar: f, masks (idx8 = prefix-8 of idxA[src_row(bq)]) ----------------
__global__ __launch_bounds__(256) void corre_kernel(
    const float* __restrict__ x, const float* __restrict__ x0vec,
    const float* __restrict__ w_reduce, const int* __restrict__ idxA,
    float* __restrict__ fbuf, float* __restrict__ masks)
{
    __shared__ float sxv[64], sq[64], ss[512], sfk[512];
    int bq = blockIdx.x, tid = threadIdx.x;
    int row = src_row(bq);
    const float* Xb = x + (size_t)row * 32768;
    if (tid < 64) sxv[tid] = x0vec[bq * 64 + tid];
    __syncthreads();
    if (tid < 64) {
        float a = 0.f;
        for (int c = 0; c < 64; ++c) a += w_reduce[tid * 64 + c] * sxv[c];
        sq[tid] = a;
    }
    __syncthreads();
    for (int i = tid; i < 512; i += 256) {
        float a = 0.f;
        for (int c = 0; c < 64; ++c) a += sq[c] * Xb[c * 512 + i];
        a *= 0.125f;
        ss[i] = a;
        fbuf[bq * 512 + i] = a;
    }
    __syncthreads();
    for (int i = tid; i < 512; i += 256) {
        float a = ss[i];
        const int* ip = idxA + ((size_t)row * 512 + i) * 16;
        for (int q = 0; q < 8; ++q) a += ss[ip[q]];
        sfk[i] = a;
    }
    masks[bq * 512 + tid] = 1.0f;
    masks[bq * 512 + tid + 256] = 1.0f;
    __syncthreads();
    if (tid == 0) {
        float best = sfk[0]; int bi = 0;
        for (int i = 1; i < 512; ++i) if (sfk[i] > best) { best = sfk[i]; bi = i; }
        masks[bq * 512 + bi] = 0.f;
        const int* ip = idxA + ((size_t)row * 512 + bi) * 16;
        for (int q = 0; q < 8; ++q) masks[bq * 512 + ip[q]] = 0.f;
    }
}

// ---------------- erase1 slim: y1 = BN(W_e @ softmax-pooled + b_e); bias1 = W2_1 @ y1 ----------------
__global__ __launch_bounds__(256) void erase1_kernel(
    const float* __restrict__ x, const float* __restrict__ masks,
    const float* __restrict__ fbuf,
    const float* __restrict__ w_e, const float* __restrict__ b_e,
    const float* __restrict__ g_e, const float* __restrict__ be_e,
    const float* __restrict__ m_e, const float* __restrict__ v_e,
    const float* __restrict__ w1, float* __restrict__ bias1)
{
    __shared__ float sw[512];
    __shared__ float red[256];
    __shared__ float sres[64];
    __shared__ float sy[64];
    int bq = blockIdx.x, tid = threadIdx.x;
    int row = src_row(bq);
    const float* Xb = x + (size_t)row * 32768;
    float f0 = fbuf[bq * 512 + tid], f1 = fbuf[bq * 512 + tid + 256];
    float mk0 = masks[bq * 512 + tid], mk1 = masks[bq * 512 + tid + 256];
    float s0 = f0 - (1.f - mk0) * 1e8f, s1 = f1 - (1.f - mk1) * 1e8f;
    red[tid] = fmaxf(s0, s1);
    __syncthreads();
    for (int off = 128; off >= 1; off >>= 1) {
        if (tid < off) red[tid] = fmaxf(red[tid], red[tid + off]);
        __syncthreads();
    }
    float mx = red[0];
    __syncthreads();
    float e0 = expf(s0 - mx), e1 = expf(s1 - mx);
    red[tid] = e0 + e1;
    __syncthreads();
    for (int off = 128; off >= 1; off >>= 1) {
        if (tid < off) red[tid] = red[tid] + red[tid + off];
        __syncthreads();
    }
    float inv = 1.f / red[0];
    __syncthreads();
    sw[tid] = e0 * inv; sw[tid + 256] = e1 * inv;
    __syncthreads();
    int c4 = tid >> 2, p4 = tid & 3;
    {
        float a = 0.f;
        const float* xr = Xb + c4 * 512 + p4 * 128;
        const float* wr = &sw[p4 * 128];
        for (int ii = 0; ii < 128; ++ii) a += xr[ii] * wr[ii];
        red[tid] = a;
    }
    __syncthreads();
    if (p4 == 0) sres[c4] = red[tid] + red[tid + 1] + red[tid + 2] + red[tid + 3];
    __syncthreads();
    if (tid < 64) {
        float a = b_e[tid];
        for (int cc = 0; cc < 64; ++cc) a += w_e[tid * 64 + cc] * sres[cc];
        float sc = g_e[tid] / sqrtf(v_e[tid] + EPS);
        sy[tid] = (a - m_e[tid]) * sc + be_e[tid];
    }
    __syncthreads();
    if (tid < 64) {
        float a = 0.f;
        for (int cc = 0; cc < 64; ++cc) a += w1[tid * 128 + 64 + cc] * sy[cc];
        bias1[bq * 64 + tid] = a;
    }
}

extern "C" void kernel_launch(void* const* d_in, const int* in_sizes, int n_in,
                              void* d_out, int out_size, void* d_ws, size_t ws_size,
                              hipStream_t stream)
{
    const float* x        = (const float*)d_in[0];
    const float* w_reduce = (const float*)d_in[1];
    const float* w_erase  = (const float*)d_in[2];
    const float* b_erase  = (const float*)d_in[3];
    const float* g_erase  = (const float*)d_in[4];
    const float* be_erase = (const float*)d_in[5];
    const float* m_erase  = (const float*)d_in[6];
    const float* v_erase  = (const float*)d_in[7];
    const float* w0 = (const float*)d_in[8];
    const float* g0 = (const float*)d_in[9];
    const float* b0 = (const float*)d_in[10];
    const float* m0 = (const float*)d_in[11];
    const float* v0 = (const float*)d_in[12];
    const float* w1 = (const float*)d_in[13];
    const float* g1 = (const float*)d_in[14];
    const float* b1 = (const float*)d_in[15];
    const float* m1 = (const float*)d_in[16];
    const float* v1 = (const float*)d_in[17];
    float* out = (float*)d_out;
    char* ws = (char*)d_ws;

    _Float16* h0 = (_Float16*)(ws);              // 6.29 MB  split of raw x
    _Float16* l0 = (_Float16*)(ws + 6291456);    // 6.29 MB
    int*   idxA  = (int*)(ws + 12582912);        // 3.15 MB
    int*   idxB  = (int*)(ws + 15728640);        // 3.15 MB
    float* xn0   = (float*)(ws + 18874368);      // 192 KB
    float* bias0 = (float*)(ws + 19070976);      // 24 KB
    float* bias1 = (float*)(ws + 19095552);      // 24 KB
    float* x0vec = (float*)(ws + 19120128);      // 24 KB
    float* fbuf  = (float*)(ws + 19144704);      // 192 KB
    float* masks = (float*)(ws + 19341312);      // 192 KB
    _Float16* wh0 = (_Float16*)(ws + 19537920);  // 16 KB
    _Float16* wl0 = (_Float16*)(ws + 19554304);  // 16 KB
    _Float16* wh1 = (_Float16*)(ws + 19570688);  // 16 KB
    _Float16* wl1 = (_Float16*)(ws + 19587072);  // 16 KB

    (void)in_sizes; (void)n_in; (void)out_size; (void)ws_size;

    prep_kernel<<<768, 256, 0, stream>>>(x, h0, l0, xn0, w0, w1, wh0, wl0, wh1, wl1);
    knn_kernel<0><<<768, 256, 0, stream>>>(h0, l0, xn0, nullptr, 0, idxA, 10);
    erase0_kernel<<<96, 256, 0, stream>>>(x, w0, w_erase, b_erase, g_erase, be_erase, m_erase, v_erase, bias0);
    fused_branch_kernel<0><<<dim3(96, 8), 256, 0, stream>>>(h0, l0, wh0, wl0, idxA, nullptr, 0, bias0,
                                                            g0, b0, m0, v0, out, x0vec);
    corre_kernel<<<96, 256, 0, stream>>>(x, x0vec, w_reduce, idxA, fbuf, masks);
    erase1_kernel<<<96, 256, 0, stream>>>(x, masks, fbuf, w_erase, b_erase, g_erase, be_erase, m_erase, v_erase,
                                          w1, bias1);
    knn_kernel<1><<<768, 256, 0, stream>>>(h0, l0, xn0, masks, 1, idxB, 10);
    fused_branch_kernel<1><<<dim3(96, 8), 256, 0, stream>>>(h0, l0, wh1, wl1, idxB, masks, 1, bias1,
                                                            g1, b1, m1, v1, out, nullptr);
}

// Round 14
// 254.993 us; speedup vs baseline: 1.0976x; 1.0976x over previous
//
#include <hip/hip_runtime.h>
#include <math.h>

#define EPS 1e-5f

typedef _Float16 half8 __attribute__((ext_vector_type(8)));
typedef float f32x4 __attribute__((ext_vector_type(4)));

// H/L global layout per row: [tile(8)][chunk(8)][col(64)] x 8 halves (16B units).

// bq in [0,96): b = bq/12, t = bq%12; x1seq row = b*12 + min(t+1, 11)
__device__ __forceinline__ int src_row(int bq) {
    int b = bq / 12, t = bq - b * 12;
    int t2 = (t + 1 < 12) ? (t + 1) : 11;
    return b * 12 + t2;
}

// ---------------- prep (768 blocks) + erase0 (96 blocks) fused ----------------
// raw < 768: fp16 split of raw x (chunk layout) + colnorms; raw<2 also W' splits.
// raw >= 768: erase0 for bq = raw-768 -> bias0.
__global__ __launch_bounds__(256) void prep_kernel(
    const float* __restrict__ X,
    _Float16* __restrict__ H, _Float16* __restrict__ L, float* __restrict__ xn,
    const float* __restrict__ w0, const float* __restrict__ w1,
    _Float16* __restrict__ wh0, _Float16* __restrict__ wl0,
    _Float16* __restrict__ wh1, _Float16* __restrict__ wl1,
    const float* __restrict__ w_e, const float* __restrict__ b_e,
    const float* __restrict__ g_e, const float* __restrict__ be_e,
    const float* __restrict__ m_e, const float* __restrict__ v_e,
    float* __restrict__ bias0)
{
    __shared__ float lds[64 * 65];
    __shared__ float xnp[4 * 64];
    __shared__ float part[256];
    __shared__ float res[64];
    __shared__ float sy[64];
    int raw = blockIdx.x;
    int tid = threadIdx.x;
    if (raw >= 768) {
        // ---- erase0: y0 = BN(W_e @ mean_n(x) + b_e); bias0 = W2_0 @ y0 ----
        int bq = raw - 768;
        int c = tid >> 2, p = tid & 3;
        const float* xb = X + (size_t)bq * 32768 + c * 512 + p * 128;
        float acc = 0.f;
        for (int ii = 0; ii < 128; ii += 4) {
            float4 v = *(const float4*)(xb + ii);
            acc += v.x + v.y + v.z + v.w;
        }
        part[tid] = acc;
        __syncthreads();
        if (p == 0) res[c] = (part[tid] + part[tid+1] + part[tid+2] + part[tid+3]) * (1.f/512.f);
        __syncthreads();
        if (tid < 64) {
            float a = b_e[tid];
            for (int cc = 0; cc < 64; ++cc) a += w_e[tid*64+cc] * res[cc];
            float s = g_e[tid] / sqrtf(v_e[tid] + EPS);
            sy[tid] = (a - m_e[tid]) * s + be_e[tid];
        }
        __syncthreads();
        if (tid < 64) {
            float a = 0.f;
            for (int cc = 0; cc < 64; ++cc) a += w0[tid * 128 + 64 + cc] * sy[cc];
            bias0[bq * 64 + tid] = a;
        }
        return;
    }
    int bq = raw % 96;
    int ct = raw / 96;
    const float* Xb = X + (size_t)bq * 32768 + ct * 64;
    for (int p = 0; p < 16; ++p) {
        int t = p * 256 + tid;
        int c = t >> 6, col = t & 63;
        lds[c * 65 + col] = Xb[c * 512 + col];
    }
    __syncthreads();
    int col = tid & 63, g = tid >> 6;
    half8 hv[2], lv[2];
    float s = 0.f;
    #pragma unroll
    for (int k = 0; k < 16; ++k) {
        int c = g * 16 + k;
        float v = lds[c * 65 + col];
        _Float16 h = (_Float16)v;
        _Float16 lo = (_Float16)(v - (float)h);
        hv[k >> 3][k & 7] = h;
        lv[k >> 3][k & 7] = lo;
        s += v * v;
    }
    size_t obase = (size_t)bq * 32768 + ((size_t)(ct * 8 + 2 * g) * 64 + col) * 8;
    *(half8*)(H + obase) = hv[0];
    *(half8*)(H + obase + 512) = hv[1];
    *(half8*)(L + obase) = lv[0];
    *(half8*)(L + obase + 512) = lv[1];
    xnp[g * 64 + col] = s;
    __syncthreads();
    if (tid < 64)
        xn[bq * 512 + ct * 64 + tid] =
            xnp[tid] + xnp[64 + tid] + xnp[128 + tid] + xnp[192 + tid];
    if (raw < 2) {
        const float* W = raw ? w1 : w0;
        _Float16* WH = raw ? wh1 : wh0;
        _Float16* WL = raw ? wl1 : wl0;
        for (int t = tid; t < 8192; t += 256) {
            int o = t >> 6, c = t & 63;
            float v = (o < 64) ? W[o * 128 + c]
                               : (W[(o - 64) * 128 + 64 + c] - W[(o - 64) * 128 + c]);
            _Float16 h = (_Float16)v;
            WH[t] = h;
            WL[t] = (_Float16)(v - (float)h);
        }
    }
}

// ---------------- kNN v6 (R13, unchanged): mask in epilogue, plain staging ----------------
template<int MASKED>
__global__ __launch_bounds__(256, 5) void knn_kernel(
    const _Float16* __restrict__ H, const _Float16* __restrict__ L,
    const float* __restrict__ xn, const float* __restrict__ masks, int remap,
    int* __restrict__ idx_out, int K)
{
    __shared__ float4 jbufH4[512];
    __shared__ float4 jbufL4[512];
    __shared__ float smask[MASKED ? 512 : 4];
    __shared__ unsigned ldsMV[4][64 * 11];
    __shared__ unsigned short ldsMJ[4][64 * 11];
    int raw = blockIdx.x;
    int bq = raw % 96;
    int itile = raw / 96;
    int row = remap ? src_row(bq) : bq;
    int tid = threadIdx.x, w = tid >> 6, l = tid & 63;
    int lane16 = l & 15, quad = l >> 4;
    const size_t base = (size_t)row * 32768;
    const _Float16* Hb = H + base;
    const _Float16* Lb = L + base;
    if (MASKED) {
        smask[tid] = masks[bq * 512 + tid];
        smask[tid + 256] = masks[bq * 512 + tid + 256];
    }
    int irow = itile * 64 + w * 16 + lane16;
    size_t bo = ((size_t)(itile * 8 + quad) * 64 + (w * 16 + lane16)) * 8;
    half8 Bh0 = *(const half8*)(Hb + bo);
    half8 Bh1 = *(const half8*)(Hb + bo + 2048);
    half8 Bl0 = *(const half8*)(Lb + bo);
    half8 Bl1 = *(const half8*)(Lb + bo + 2048);
    float mi2 = 2.f;
    if (MASKED) mi2 = 2.f * masks[bq * 512 + irow];

    unsigned kv[10]; int kj[10];
    #pragma unroll
    for (int qq = 0; qq < 10; ++qq) { kv[qq] = 0u; kj[qq] = 0; }

    auto casu = [](unsigned& a, unsigned& b) {
        unsigned mn = a < b ? a : b;
        unsigned mx = a < b ? b : a;
        a = mn; b = mx;
    };
    auto cas_kj = [](unsigned& ka, int& ja, unsigned& kb, int& jb2) {
        bool sw = ka > kb;
        unsigned tk = ka; int tj = ja;
        ka = sw ? kb : ka; ja = sw ? jb2 : ja;
        kb = sw ? tk : kb; jb2 = sw ? tj : jb2;
    };

    const float* xnb = xn + row * 512;
    const _Float16* jH = (const _Float16*)jbufH4;
    const _Float16* jL = (const _Float16*)jbufL4;
    float4 pa0, pa1, pb0, pb1;
    {
        const float4* gh = (const float4*)(Hb);
        const float4* gl = (const float4*)(Lb);
        pa0 = gh[tid]; pa1 = gh[256 + tid];
        pb0 = gl[tid]; pb1 = gl[256 + tid];
    }
    for (int jt = 0; jt < 8; ++jt) {
        if (jt) __syncthreads();
        jbufH4[tid] = pa0; jbufH4[256 + tid] = pa1;
        jbufL4[tid] = pb0; jbufL4[256 + tid] = pb1;
        __syncthreads();
        unsigned d[16];
        #pragma unroll
        for (int g = 0; g < 4; ++g) {
            int u = quad * 64 + g * 16 + lane16;
            half8 Ah0 = *(const half8*)(jH + (size_t)u * 8);
            half8 Ah1 = *(const half8*)(jH + (size_t)u * 8 + 2048);
            half8 Al0 = *(const half8*)(jL + (size_t)u * 8);
            half8 Al1 = *(const half8*)(jL + (size_t)u * 8 + 2048);
            f32x4 acc = {0.f, 0.f, 0.f, 0.f};
            acc = __builtin_amdgcn_mfma_f32_16x16x32_f16(Ah0, Bh0, acc, 0, 0, 0);
            acc = __builtin_amdgcn_mfma_f32_16x16x32_f16(Ah1, Bh1, acc, 0, 0, 0);
            acc = __builtin_amdgcn_mfma_f32_16x16x32_f16(Al0, Bh0, acc, 0, 0, 0);
            acc = __builtin_amdgcn_mfma_f32_16x16x32_f16(Al1, Bh1, acc, 0, 0, 0);
            acc = __builtin_amdgcn_mfma_f32_16x16x32_f16(Ah0, Bl0, acc, 0, 0, 0);
            acc = __builtin_amdgcn_mfma_f32_16x16x32_f16(Ah1, Bl1, acc, 0, 0, 0);
            int jb = jt * 64 + g * 16 + quad * 4;
            float4 xn4 = *(const float4*)&xnb[jb];
            float4 mj4;
            if (MASKED) mj4 = *(const float4*)&smask[jb];
            #pragma unroll
            for (int r = 0; r < 4; ++r) {
                float xnr = (r == 0 ? xn4.x : r == 1 ? xn4.y : r == 2 ? xn4.z : xn4.w);
                float sc = fmaf(mi2, acc[r], -xnr);
                if (MASKED) {
                    float mjr = (r == 0 ? mj4.x : r == 1 ? mj4.y : r == 2 ? mj4.z : mj4.w);
                    sc = (mjr != 0.f) ? sc : 0.0f;
                }
                int bi = __float_as_int(sc);
                unsigned u2 = (unsigned)(bi ^ ((bi >> 31) | 0x80000000));
                int slot = g * 4 + r;
                d[slot] = (u2 & 0xFFFFFFF0u) | (unsigned)(15 - slot);
            }
        }
        if (jt < 7) {
            const float4* gh = (const float4*)(Hb + (jt + 1) * 4096);
            const float4* gl = (const float4*)(Lb + (jt + 1) * 4096);
            pa0 = gh[tid]; pa1 = gh[256 + tid];
            pb0 = gl[tid]; pb1 = gl[256 + tid];
        }
        #pragma unroll
        for (int p = 1; p < 16; p <<= 1) {
            #pragma unroll
            for (int k = p; k >= 1; k >>= 1) {
                #pragma unroll
                for (int j = k & (p - 1); j + k < 16; j += 2 * k) {
                    #pragma unroll
                    for (int i = 0; i < k; ++i) {
                        if ((i + j + k < 16) &&
                            ((i + j) / (2 * p) == (i + j + k) / (2 * p)))
                            casu(d[i + j], d[i + j + k]);
                    }
                }
            }
        }
        #pragma unroll
        for (int i = 0; i < 10; ++i) {
            unsigned dv = d[15 - i];
            int code = 15 - (int)(dv & 15u);
            int jnew = jt * 64 + (code >> 2) * 16 + quad * 4 + (code & 3);
            bool keep = kv[i] >= dv;
            kj[i] = keep ? kj[i] : jnew;
            kv[i] = keep ? kv[i] : dv;
        }
        cas_kj(kv[0], kj[0], kv[8], kj[8]);
        cas_kj(kv[1], kj[1], kv[9], kj[9]);
        cas_kj(kv[0], kj[0], kv[4], kj[4]);
        cas_kj(kv[1], kj[1], kv[5], kj[5]);
        cas_kj(kv[2], kj[2], kv[6], kj[6]);
        cas_kj(kv[3], kj[3], kv[7], kj[7]);
        cas_kj(kv[0], kj[0], kv[2], kj[2]);
        cas_kj(kv[1], kj[1], kv[3], kj[3]);
        cas_kj(kv[4], kj[4], kv[6], kj[6]);
        cas_kj(kv[5], kj[5], kv[7], kj[7]);
        cas_kj(kv[0], kj[0], kv[1], kj[1]);
        cas_kj(kv[2], kj[2], kv[3], kj[3]);
        cas_kj(kv[4], kj[4], kv[5], kj[5]);
        cas_kj(kv[6], kj[6], kv[7], kj[7]);
        cas_kj(kv[8], kj[8], kv[9], kj[9]);
    }
    #pragma unroll
    for (int qq = 0; qq < 10; ++qq) {
        ldsMV[w][(lane16 * 4 + quad) * 11 + qq] = kv[qq];
        ldsMJ[w][(lane16 * 4 + quad) * 11 + qq] = (unsigned short)kj[qq];
    }
    __syncthreads();
    if (quad == 0) {
        const unsigned* MV = &ldsMV[w][lane16 * 44];
        const unsigned short* MJ = &ldsMJ[w][lane16 * 44];
        int p0 = 9, p1 = 9, p2 = 9, p3 = 9;
        int* op = idx_out + ((size_t)bq * 512 + irow) * 16;
        for (int t = 0; t < K; ++t) {
            unsigned bv = 0u; int bj = 0x7fffffff; int bc = -1;
            { unsigned v = MV[p0]; int j = MJ[p0];
              if (v > bv || (v == bv && j < bj)) { bv = v; bj = j; bc = 0; } }
            { unsigned v = MV[11 + p1]; int j = MJ[11 + p1];
              if (v > bv || (v == bv && j < bj)) { bv = v; bj = j; bc = 1; } }
            { unsigned v = MV[22 + p2]; int j = MJ[22 + p2];
              if (v > bv || (v == bv && j < bj)) { bv = v; bj = j; bc = 2; } }
            { unsigned v = MV[33 + p3]; int j = MJ[33 + p3];
              if (v > bv || (v == bv && j < bj)) { bv = v; bj = j; bc = 3; } }
            if (bc == 0) --p0; else if (bc == 1) --p1; else if (bc == 2) --p2; else --p3;
            op[t] = bj;
        }
    }
}

// ---------------- fused branch (R13, unchanged): grid (96,8) ----------------
template<int ACC>
__global__ void __attribute__((amdgpu_flat_work_group_size(256, 256), amdgpu_waves_per_eu(2, 4)))
fused_branch_kernel(
    const _Float16* __restrict__ H, const _Float16* __restrict__ L,
    const _Float16* __restrict__ WH, const _Float16* __restrict__ WL,
    const int* __restrict__ idx, const float* __restrict__ masks, int remap,
    const float* __restrict__ bias,
    const float* __restrict__ g, const float* __restrict__ bb,
    const float* __restrict__ mm, const float* __restrict__ vv,
    float* __restrict__ out_p, float* __restrict__ vec_out)
{
    __shared__ float ldsA[8 * 512];
    __shared__ float ldsB[8 * 512];
    __shared__ unsigned short ldsIdx[512 * 10];
    __shared__ float smask[512];
    int bq = blockIdx.x, ob = blockIdx.y * 8;
    int row = remap ? src_row(bq) : bq;
    bool use_mask = (masks != nullptr);
    int tid = threadIdx.x, w = tid >> 6, l = tid & 63;
    int lane16 = l & 15, quad = l >> 4;
    const size_t base = (size_t)row * 32768;
    for (int p = 0; p < 20; ++p) {
        int t = p * 256 + tid;
        int i = t / 10, q = t - i * 10;
        ldsIdx[t] = (unsigned short)idx[((size_t)bq * 512 + i) * 16 + q];
    }
    if (use_mask) {
        smask[tid] = masks[bq * 512 + tid];
        smask[tid + 256] = masks[bq * 512 + tid + 256];
    }
    __syncthreads();
    {
        int wrow = (lane16 < 8) ? (ob + lane16) : (64 + ob + (lane16 - 8));
        size_t woff = (size_t)wrow * 64 + quad * 8;
        half8 Ah0 = *(const half8*)(WH + woff);
        half8 Ah1 = *(const half8*)(WH + woff + 32);
        half8 Al0 = *(const half8*)(WL + woff);
        half8 Al1 = *(const half8*)(WL + woff + 32);
        float* dst = (quad < 2) ? (ldsA + (quad * 4) * 512) : (ldsB + ((quad - 2) * 4) * 512);
        for (int k = 0; k < 8; ++k) {
            int it = w * 8 + k;
            size_t off = base + (((size_t)(it >> 2) * 8 + quad) * 64 + (it & 3) * 16 + lane16) * 8;
            half8 Xh0 = *(const half8*)(H + off);
            half8 Xh1 = *(const half8*)(H + off + 2048);
            half8 Xl0 = *(const half8*)(L + off);
            half8 Xl1 = *(const half8*)(L + off + 2048);
            if (use_mask) {
                float m = smask[it * 16 + lane16];
                if (m == 0.f) {
                    half8 z = {};
                    Xh0 = z; Xh1 = z; Xl0 = z; Xl1 = z;
                }
            }
            f32x4 acc = {0.f, 0.f, 0.f, 0.f};
            acc = __builtin_amdgcn_mfma_f32_16x16x32_f16(Ah0, Xh0, acc, 0, 0, 0);
            acc = __builtin_amdgcn_mfma_f32_16x16x32_f16(Ah1, Xh1, acc, 0, 0, 0);
            acc = __builtin_amdgcn_mfma_f32_16x16x32_f16(Ah0, Xl0, acc, 0, 0, 0);
            acc = __builtin_amdgcn_mfma_f32_16x16x32_f16(Ah1, Xl1, acc, 0, 0, 0);
            acc = __builtin_amdgcn_mfma_f32_16x16x32_f16(Al0, Xh0, acc, 0, 0, 0);
            acc = __builtin_amdgcn_mfma_f32_16x16x32_f16(Al1, Xh1, acc, 0, 0, 0);
            #pragma unroll
            for (int r = 0; r < 4; ++r)
                dst[r * 512 + it * 16 + lane16] = acc[r];
        }
    }
    __syncthreads();
    float ssr[2], str[2];
    #pragma unroll
    for (int oo = 0; oo < 2; ++oo) {
        int o = ob + w * 2 + oo;
        float sc = g[o] / sqrtf(vv[o] + EPS);
        ssr[oo] = sc;
        str[oo] = bb[o] - mm[o] * sc + bias[bq * 64 + o] * sc;
    }
    float omax[2], osum[2];
    #pragma unroll
    for (int oo = 0; oo < 2; ++oo) { omax[oo] = -3.4e38f; osum[oo] = 0.f; }
    const float* Aw = ldsA + (w * 2) * 512;
    const float* Bw = ldsB + (w * 2) * 512;
    for (int s = 0; s < 8; ++s) {
        int i = l + 64 * s;
        int idr[10];
        const unsigned short* ip = &ldsIdx[i * 10];
        #pragma unroll
        for (int q = 0; q < 10; ++q) idr[q] = ip[q];
        #pragma unroll
        for (int oo = 0; oo < 2; ++oo) {
            const float* Ao = Aw + oo * 512;
            float mx = Ao[idr[0]];
            #pragma unroll
            for (int q = 1; q < 10; ++q) mx = fmaxf(mx, Ao[idr[q]]);
            float val = (mx + Bw[oo * 512 + i]) * ssr[oo] + str[oo];
            float y = val > 0.f ? val : 0.2f * val;
            omax[oo] = fmaxf(omax[oo], y);
            osum[oo] += y;
        }
    }
    #pragma unroll
    for (int oo = 0; oo < 2; ++oo) {
        float M = omax[oo], S = osum[oo];
        #pragma unroll
        for (int off = 32; off >= 1; off >>= 1) {
            M = fmaxf(M, __shfl_down(M, off));
            S += __shfl_down(S, off);
        }
        if (l == 0) {
            int o = ob + w * 2 + oo;
            float* po = out_p + bq * 128;
            if (ACC) {
                po[o] += M;
                po[64 + o] += S * (1.f / 512.f);
            } else {
                po[o] = M;
                po[64 + o] = S * (1.f / 512.f);
                vec_out[bq * 64 + o] = M;
            }
        }
    }
}

// ---------------- corre + erase1 fused: masks + bias1 in one 96-block kernel ----------------
__global__ __launch_bounds__(256) void corre_erase1_kernel(
    const float* __restrict__ x, const float* __restrict__ x0vec,
    const float* __restrict__ w_reduce, const int* __restrict__ idxA,
    const float* __restrict__ w_e, const float* __restrict__ b_e,
    const float* __restrict__ g_e, const float* __restrict__ be_e,
    const float* __restrict__ m_e, const float* __restrict__ v_e,
    const float* __restrict__ w1,
    float* __restrict__ masks, float* __restrict__ bias1)
{
    __shared__ float sxv[64], sq[64];
    __shared__ float ss[512], sfk[512], smk[512];
    __shared__ float red[256];
    __shared__ float redv[4]; __shared__ int redi[4];
    __shared__ float sres[64], sy[64];
    int bq = blockIdx.x, tid = threadIdx.x;
    int row = src_row(bq);
    const float* Xb = x + (size_t)row * 32768;
    if (tid < 64) sxv[tid] = x0vec[bq * 64 + tid];
    __syncthreads();
    if (tid < 64) {
        float a = 0.f;
        for (int c = 0; c < 64; ++c) a += w_reduce[tid * 64 + c] * sxv[c];
        sq[tid] = a;
    }
    __syncthreads();
    for (int i = tid; i < 512; i += 256) {
        float a = 0.f;
        for (int c = 0; c < 64; ++c) a += sq[c] * Xb[c * 512 + i];
        ss[i] = a * 0.125f;                 // f values (fbuf, kept in LDS)
    }
    __syncthreads();
    for (int i = tid; i < 512; i += 256) {
        float a = ss[i];
        const int* ip = idxA + ((size_t)row * 512 + i) * 16;
        for (int q = 0; q < 8; ++q) a += ss[ip[q]];
        sfk[i] = a;
        smk[i] = 1.0f;
    }
    __syncthreads();
    // wave-parallel argmax of sfk with first-occurrence (min index) tie-break
    {
        float bv = sfk[tid]; int bi = tid;
        float v1 = sfk[tid + 256];
        if (v1 > bv) { bv = v1; bi = tid + 256; }
        #pragma unroll
        for (int off = 32; off >= 1; off >>= 1) {
            float ov = __shfl_down(bv, off);
            int oi = __shfl_down(bi, off);
            if (ov > bv || (ov == bv && oi < bi)) { bv = ov; bi = oi; }
        }
        int w = tid >> 6, l = tid & 63;
        if (l == 0) { redv[w] = bv; redi[w] = bi; }
    }
    __syncthreads();
    if (tid == 0) {
        float Bv = redv[0]; int Bi = redi[0];
        for (int w = 1; w < 4; ++w)
            if (redv[w] > Bv || (redv[w] == Bv && redi[w] < Bi)) { Bv = redv[w]; Bi = redi[w]; }
        smk[Bi] = 0.f;
        const int* ip = idxA + ((size_t)row * 512 + Bi) * 16;
        for (int q = 0; q < 8; ++q) smk[ip[q]] = 0.f;
    }
    __syncthreads();
    masks[bq * 512 + tid] = smk[tid];
    masks[bq * 512 + tid + 256] = smk[tid + 256];
    // ---- erase1: softmax pooling over masked f, BN, bias1 = W2_1 @ y1 ----
    float mk0 = smk[tid], mk1 = smk[tid + 256];
    float s0 = ss[tid] - (1.f - mk0) * 1e8f, s1 = ss[tid + 256] - (1.f - mk1) * 1e8f;
    red[tid] = fmaxf(s0, s1);
    __syncthreads();
    for (int off = 128; off >= 1; off >>= 1) {
        if (tid < off) red[tid] = fmaxf(red[tid], red[tid + off]);
        __syncthreads();
    }
    float mx = red[0];
    __syncthreads();
    float e0 = expf(s0 - mx), e1 = expf(s1 - mx);
    red[tid] = e0 + e1;
    __syncthreads();
    for (int off = 128; off >= 1; off >>= 1) {
        if (tid < off) red[tid] = red[tid] + red[tid + off];
        __syncthreads();
    }
    float inv = 1.f / red[0];
    __syncthreads();
    sfk[tid] = e0 * inv; sfk[tid + 256] = e1 * inv;   // reuse sfk as softmax weights
    __syncthreads();
    int c4 = tid >> 2, p4 = tid & 3;
    {
        float a = 0.f;
        const float* xr = Xb + c4 * 512 + p4 * 128;
        const float* wr = &sfk[p4 * 128];
        for (int ii = 0; ii < 128; ++ii) a += xr[ii] * wr[ii];
        red[tid] = a;
    }
    __syncthreads();
    if (p4 == 0) sres[c4] = red[tid] + red[tid + 1] + red[tid + 2] + red[tid + 3];
    __syncthreads();
    if (tid < 64) {
        float a = b_e[tid];
        for (int cc = 0; cc < 64; ++cc) a += w_e[tid * 64 + cc] * sres[cc];
        float sc = g_e[tid] / sqrtf(v_e[tid] + EPS);
        sy[tid] = (a - m_e[tid]) * sc + be_e[tid];
    }
    __syncthreads();
    if (tid < 64) {
        float a = 0.f;
        for (int cc = 0; cc < 64; ++cc) a += w1[tid * 128 + 64 + cc] * sy[cc];
        bias1[bq * 64 + tid] = a;
    }
}

extern "C" void kernel_launch(void* const* d_in, const int* in_sizes, int n_in,
                              void* d_out, int out_size, void* d_ws, size_t ws_size,
                              hipStream_t stream)
{
    const float* x        = (const float*)d_in[0];
    const float* w_reduce = (const float*)d_in[1];
    const float* w_erase  = (const float*)d_in[2];
    const float* b_erase  = (const float*)d_in[3];
    const float* g_erase  = (const float*)d_in[4];
    const float* be_erase = (const float*)d_in[5];
    const float* m_erase  = (const float*)d_in[6];
    const float* v_erase  = (const float*)d_in[7];
    const float* w0 = (const float*)d_in[8];
    const float* g0 = (const float*)d_in[9];
    const float* b0 = (const float*)d_in[10];
    const float* m0 = (const float*)d_in[11];
    const float* v0 = (const float*)d_in[12];
    const float* w1 = (const float*)d_in[13];
    const float* g1 = (const float*)d_in[14];
    const float* b1 = (const float*)d_in[15];
    const float* m1 = (const float*)d_in[16];
    const float* v1 = (const float*)d_in[17];
    float* out = (float*)d_out;
    char* ws = (char*)d_ws;

    _Float16* h0 = (_Float16*)(ws);              // 6.29 MB  split of raw x
    _Float16* l0 = (_Float16*)(ws + 6291456);    // 6.29 MB
    int*   idxA  = (int*)(ws + 12582912);        // 3.15 MB
    int*   idxB  = (int*)(ws + 15728640);        // 3.15 MB
    float* xn0   = (float*)(ws + 18874368);      // 192 KB
    float* bias0 = (float*)(ws + 19070976);      // 24 KB
    float* bias1 = (float*)(ws + 19095552);      // 24 KB
    float* x0vec = (float*)(ws + 19120128);      // 24 KB
    float* masks = (float*)(ws + 19144704);      // 192 KB
    _Float16* wh0 = (_Float16*)(ws + 19341312);  // 16 KB
    _Float16* wl0 = (_Float16*)(ws + 19357696);  // 16 KB
    _Float16* wh1 = (_Float16*)(ws + 19374080);  // 16 KB
    _Float16* wl1 = (_Float16*)(ws + 19390464);  // 16 KB

    (void)in_sizes; (void)n_in; (void)out_size; (void)ws_size;

    // 1. prep (768) + erase0 (96)  [erase0 independent, rides along]
    prep_kernel<<<864, 256, 0, stream>>>(x, h0, l0, xn0, w0, w1, wh0, wl0, wh1, wl1,
                                         w_erase, b_erase, g_erase, be_erase, m_erase, v_erase, bias0);
    // 2. kNN on x (translation-invariant: same as kNN on x0)
    knn_kernel<0><<<768, 256, 0, stream>>>(h0, l0, xn0, nullptr, 0, idxA, 10);
    // 3. branch 0
    fused_branch_kernel<0><<<dim3(96, 8), 256, 0, stream>>>(h0, l0, wh0, wl0, idxA, nullptr, 0, bias0,
                                                            g0, b0, m0, v0, out, x0vec);
    // 4. corre_binar + erase1 fused -> masks, bias1
    corre_erase1_kernel<<<96, 256, 0, stream>>>(x, x0vec, w_reduce, idxA,
                                                w_erase, b_erase, g_erase, be_erase, m_erase, v_erase,
                                                w1, masks, bias1);
    // 5. masked kNN (x1e translation-reduced = masked x1seq)
    knn_kernel<1><<<768, 256, 0, stream>>>(h0, l0, xn0, masks, 1, idxB, 10);
    // 6. branch 1
    fused_branch_kernel<1><<<dim3(96, 8), 256, 0, stream>>>(h0, l0, wh1, wl1, idxB, masks, 1, bias1,
                                                            g1, b1, m1, v1, out, nullptr);
}

// Round 15
// 235.220 us; speedup vs baseline: 1.1899x; 1.0841x over previous
//
#include <hip/hip_runtime.h>
#include <math.h>

#define EPS 1e-5f

typedef _Float16 half8 __attribute__((ext_vector_type(8)));
typedef float f32x4 __attribute__((ext_vector_type(4)));

// H/L global layout per row: [tile(8)][chunk(8)][col(64)] x 8 halves (16B units).

// bq in [0,96): b = bq/12, t = bq%12; x1seq row = b*12 + min(t+1, 11)
__device__ __forceinline__ int src_row(int bq) {
    int b = bq / 12, t = bq - b * 12;
    int t2 = (t + 1 < 12) ? (t + 1) : 11;
    return b * 12 + t2;
}

// ---------------- prep (768 blocks) + erase0 (96 blocks) fused ----------------
__global__ __launch_bounds__(256) void prep_kernel(
    const float* __restrict__ X,
    _Float16* __restrict__ H, _Float16* __restrict__ L, float* __restrict__ xn,
    const float* __restrict__ w0, const float* __restrict__ w1,
    _Float16* __restrict__ wh0, _Float16* __restrict__ wl0,
    _Float16* __restrict__ wh1, _Float16* __restrict__ wl1,
    const float* __restrict__ w_e, const float* __restrict__ b_e,
    const float* __restrict__ g_e, const float* __restrict__ be_e,
    const float* __restrict__ m_e, const float* __restrict__ v_e,
    float* __restrict__ bias0)
{
    __shared__ float lds[64 * 65];
    __shared__ float xnp[4 * 64];
    __shared__ float part[256];
    __shared__ float res[64];
    __shared__ float sy[64];
    int raw = blockIdx.x;
    int tid = threadIdx.x;
    if (raw >= 768) {
        int bq = raw - 768;
        int c = tid >> 2, p = tid & 3;
        const float* xb = X + (size_t)bq * 32768 + c * 512 + p * 128;
        float acc = 0.f;
        for (int ii = 0; ii < 128; ii += 4) {
            float4 v = *(const float4*)(xb + ii);
            acc += v.x + v.y + v.z + v.w;
        }
        part[tid] = acc;
        __syncthreads();
        if (p == 0) res[c] = (part[tid] + part[tid+1] + part[tid+2] + part[tid+3]) * (1.f/512.f);
        __syncthreads();
        if (tid < 64) {
            float a = b_e[tid];
            for (int cc = 0; cc < 64; ++cc) a += w_e[tid*64+cc] * res[cc];
            float s = g_e[tid] / sqrtf(v_e[tid] + EPS);
            sy[tid] = (a - m_e[tid]) * s + be_e[tid];
        }
        __syncthreads();
        if (tid < 64) {
            float a = 0.f;
            for (int cc = 0; cc < 64; ++cc) a += w0[tid * 128 + 64 + cc] * sy[cc];
            bias0[bq * 64 + tid] = a;
        }
        return;
    }
    int bq = raw % 96;
    int ct = raw / 96;
    const float* Xb = X + (size_t)bq * 32768 + ct * 64;
    for (int p = 0; p < 16; ++p) {
        int t = p * 256 + tid;
        int c = t >> 6, col = t & 63;
        lds[c * 65 + col] = Xb[c * 512 + col];
    }
    __syncthreads();
    int col = tid & 63, g = tid >> 6;
    half8 hv[2], lv[2];
    float s = 0.f;
    #pragma unroll
    for (int k = 0; k < 16; ++k) {
        int c = g * 16 + k;
        float v = lds[c * 65 + col];
        _Float16 h = (_Float16)v;
        _Float16 lo = (_Float16)(v - (float)h);
        hv[k >> 3][k & 7] = h;
        lv[k >> 3][k & 7] = lo;
        s += v * v;
    }
    size_t obase = (size_t)bq * 32768 + ((size_t)(ct * 8 + 2 * g) * 64 + col) * 8;
    *(half8*)(H + obase) = hv[0];
    *(half8*)(H + obase + 512) = hv[1];
    *(half8*)(L + obase) = lv[0];
    *(half8*)(L + obase + 512) = lv[1];
    xnp[g * 64 + col] = s;
    __syncthreads();
    if (tid < 64)
        xn[bq * 512 + ct * 64 + tid] =
            xnp[tid] + xnp[64 + tid] + xnp[128 + tid] + xnp[192 + tid];
    if (raw < 2) {
        const float* W = raw ? w1 : w0;
        _Float16* WH = raw ? wh1 : wh0;
        _Float16* WL = raw ? wl1 : wl0;
        for (int t = tid; t < 8192; t += 256) {
            int o = t >> 6, c = t & 63;
            float v = (o < 64) ? W[o * 128 + c]
                               : (W[(o - 64) * 128 + 64 + c] - W[(o - 64) * 128 + c]);
            _Float16 h = (_Float16)v;
            WH[t] = h;
            WL[t] = (_Float16)(v - (float)h);
        }
    }
}

// ---------------- kNN v7: double-buffered staging (1 barrier/jt); MASKED=1 fuses corre+erase1 ----
// MASKED=1: every block recomputes corre (masks) in LDS aliased over merge arrays;
// itile==0 block also runs the erase1 tail and publishes masks+bias1 for branch1.
template<int MASKED>
__global__ __launch_bounds__(256, 5) void knn_kernel(
    const _Float16* __restrict__ H, const _Float16* __restrict__ L,
    const float* __restrict__ xn, int* __restrict__ idx_out, int K,
    // corre/erase1 inputs (MASKED=1 only)
    const float* __restrict__ x, const float* __restrict__ x0vec,
    const float* __restrict__ w_reduce, const int* __restrict__ idxA,
    const float* __restrict__ w_e, const float* __restrict__ b_e,
    const float* __restrict__ g_e, const float* __restrict__ be_e,
    const float* __restrict__ m_e, const float* __restrict__ v_e,
    const float* __restrict__ w1,
    float* __restrict__ masks_out, float* __restrict__ bias1_out)
{
    __shared__ float4 jbufH4[2][512];                  // 16 KB x2
    __shared__ float4 jbufL4[2][512];
    __shared__ float smask[MASKED ? 512 : 4];
    __shared__ unsigned ldsMV[4][64 * 11];             // 11 KB (aliased by corre scratch)
    __shared__ unsigned short ldsMJ[4][64 * 11];       // 5.5 KB
    int raw = blockIdx.x;
    int bq = raw % 96;
    int itile = raw / 96;
    int row = MASKED ? src_row(bq) : bq;
    int tid = threadIdx.x, w = tid >> 6, l = tid & 63;
    int lane16 = l & 15, quad = l >> 4;
    const size_t base = (size_t)row * 32768;
    const _Float16* Hb = H + base;
    const _Float16* Lb = L + base;

    if (MASKED) {
        // ---- corre preamble (identical math/order to R14 corre_erase1) ----
        float* ss   = (float*)&ldsMV[0][0];            // 512
        float* sfk  = ss + 512;                        // 512
        float* redf = sfk + 512;                       // 256
        float* sxv  = redf + 256;                      // 64
        float* sq   = sxv + 64;                        // 64
        float* sres = sq + 64;                         // 64
        float* syy  = sres + 64;                       // 64  (6144 B total, fits 11264)
        float* redv = (float*)&ldsMJ[0][0];            // 4
        int*   redi = (int*)(redv + 4);                // 4
        const float* Xb = x + (size_t)row * 32768;
        if (tid < 64) sxv[tid] = x0vec[bq * 64 + tid];
        __syncthreads();
        if (tid < 64) {
            float a = 0.f;
            for (int c = 0; c < 64; ++c) a += w_reduce[tid * 64 + c] * sxv[c];
            sq[tid] = a;
        }
        __syncthreads();
        for (int i = tid; i < 512; i += 256) {
            float a = 0.f;
            for (int c = 0; c < 64; ++c) a += sq[c] * Xb[c * 512 + i];
            ss[i] = a * 0.125f;
        }
        __syncthreads();
        for (int i = tid; i < 512; i += 256) {
            float a = ss[i];
            const int* ip = idxA + ((size_t)row * 512 + i) * 16;
            for (int q = 0; q < 8; ++q) a += ss[ip[q]];
            sfk[i] = a;
            smask[i] = 1.0f;
        }
        __syncthreads();
        {   // wave-parallel argmax, first-occurrence tie-break
            float bv = sfk[tid]; int bi = tid;
            float v1 = sfk[tid + 256];
            if (v1 > bv) { bv = v1; bi = tid + 256; }
            #pragma unroll
            for (int off = 32; off >= 1; off >>= 1) {
                float ov = __shfl_down(bv, off);
                int oi = __shfl_down(bi, off);
                if (ov > bv || (ov == bv && oi < bi)) { bv = ov; bi = oi; }
            }
            if (l == 0) { redv[w] = bv; redi[w] = bi; }
        }
        __syncthreads();
        if (tid == 0) {
            float Bv = redv[0]; int Bi = redi[0];
            for (int ww = 1; ww < 4; ++ww)
                if (redv[ww] > Bv || (redv[ww] == Bv && redi[ww] < Bi)) { Bv = redv[ww]; Bi = redi[ww]; }
            smask[Bi] = 0.f;
            const int* ip = idxA + ((size_t)row * 512 + Bi) * 16;
            for (int q = 0; q < 8; ++q) smask[ip[q]] = 0.f;
        }
        __syncthreads();
        if (itile == 0) {
            // publish masks; erase1 tail -> bias1 (block-uniform branch, syncs legal)
            masks_out[bq * 512 + tid] = smask[tid];
            masks_out[bq * 512 + tid + 256] = smask[tid + 256];
            float mk0 = smask[tid], mk1 = smask[tid + 256];
            float s0 = ss[tid] - (1.f - mk0) * 1e8f, s1 = ss[tid + 256] - (1.f - mk1) * 1e8f;
            redf[tid] = fmaxf(s0, s1);
            __syncthreads();
            for (int off = 128; off >= 1; off >>= 1) {
                if (tid < off) redf[tid] = fmaxf(redf[tid], redf[tid + off]);
                __syncthreads();
            }
            float mx = redf[0];
            __syncthreads();
            float e0 = expf(s0 - mx), e1 = expf(s1 - mx);
            redf[tid] = e0 + e1;
            __syncthreads();
            for (int off = 128; off >= 1; off >>= 1) {
                if (tid < off) redf[tid] = redf[tid] + redf[tid + off];
                __syncthreads();
            }
            float inv = 1.f / redf[0];
            __syncthreads();
            sfk[tid] = e0 * inv; sfk[tid + 256] = e1 * inv;
            __syncthreads();
            int c4 = tid >> 2, p4 = tid & 3;
            {
                float a = 0.f;
                const float* xr = Xb + c4 * 512 + p4 * 128;
                const float* wr = &sfk[p4 * 128];
                for (int ii = 0; ii < 128; ++ii) a += xr[ii] * wr[ii];
                redf[tid] = a;
            }
            __syncthreads();
            if (p4 == 0) sres[c4] = redf[tid] + redf[tid + 1] + redf[tid + 2] + redf[tid + 3];
            __syncthreads();
            if (tid < 64) {
                float a = b_e[tid];
                for (int cc = 0; cc < 64; ++cc) a += w_e[tid * 64 + cc] * sres[cc];
                float sc = g_e[tid] / sqrtf(v_e[tid] + EPS);
                syy[tid] = (a - m_e[tid]) * sc + be_e[tid];
            }
            __syncthreads();
            if (tid < 64) {
                float a = 0.f;
                for (int cc = 0; cc < 64; ++cc) a += w1[tid * 128 + 64 + cc] * syy[cc];
                bias1_out[bq * 64 + tid] = a;
            }
        }
        __syncthreads();   // ldsMV region free; smask stable for main loop
    }

    int irow = itile * 64 + w * 16 + lane16;
    size_t bo = ((size_t)(itile * 8 + quad) * 64 + (w * 16 + lane16)) * 8;
    half8 Bh0 = *(const half8*)(Hb + bo);
    half8 Bh1 = *(const half8*)(Hb + bo + 2048);
    half8 Bl0 = *(const half8*)(Lb + bo);
    half8 Bl1 = *(const half8*)(Lb + bo + 2048);
    float mi2 = 2.f;
    if (MASKED) mi2 = 2.f * smask[irow];

    unsigned kv[10]; int kj[10];
    #pragma unroll
    for (int qq = 0; qq < 10; ++qq) { kv[qq] = 0u; kj[qq] = 0; }

    auto casu = [](unsigned& a, unsigned& b) {
        unsigned mn = a < b ? a : b;
        unsigned mx = a < b ? b : a;
        a = mn; b = mx;
    };
    auto cas_kj = [](unsigned& ka, int& ja, unsigned& kb, int& jb2) {
        bool sw = ka > kb;
        unsigned tk = ka; int tj = ja;
        ka = sw ? kb : ka; ja = sw ? jb2 : ja;
        kb = sw ? tk : kb; jb2 = sw ? tj : jb2;
    };

    const float* xnb = xn + row * 512;
    {   // stage tile 0 into buffer 0
        const float4* gh = (const float4*)(Hb);
        const float4* gl = (const float4*)(Lb);
        jbufH4[0][tid] = gh[tid]; jbufH4[0][256 + tid] = gh[256 + tid];
        jbufL4[0][tid] = gl[tid]; jbufL4[0][256 + tid] = gl[256 + tid];
    }
    __syncthreads();
    for (int jt = 0; jt < 8; ++jt) {
        int cur = jt & 1;
        float4 pa0, pa1, pb0, pb1;
        if (jt < 7) {                      // issue next-tile loads; hidden behind sort
            const float4* gh = (const float4*)(Hb + (jt + 1) * 4096);
            const float4* gl = (const float4*)(Lb + (jt + 1) * 4096);
            pa0 = gh[tid]; pa1 = gh[256 + tid];
            pb0 = gl[tid]; pb1 = gl[256 + tid];
        }
        const _Float16* jH = (const _Float16*)jbufH4[cur];
        const _Float16* jL = (const _Float16*)jbufL4[cur];
        unsigned d[16];
        #pragma unroll
        for (int g = 0; g < 4; ++g) {
            int u = quad * 64 + g * 16 + lane16;
            half8 Ah0 = *(const half8*)(jH + (size_t)u * 8);
            half8 Ah1 = *(const half8*)(jH + (size_t)u * 8 + 2048);
            half8 Al0 = *(const half8*)(jL + (size_t)u * 8);
            half8 Al1 = *(const half8*)(jL + (size_t)u * 8 + 2048);
            f32x4 acc = {0.f, 0.f, 0.f, 0.f};
            acc = __builtin_amdgcn_mfma_f32_16x16x32_f16(Ah0, Bh0, acc, 0, 0, 0);
            acc = __builtin_amdgcn_mfma_f32_16x16x32_f16(Ah1, Bh1, acc, 0, 0, 0);
            acc = __builtin_amdgcn_mfma_f32_16x16x32_f16(Al0, Bh0, acc, 0, 0, 0);
            acc = __builtin_amdgcn_mfma_f32_16x16x32_f16(Al1, Bh1, acc, 0, 0, 0);
            acc = __builtin_amdgcn_mfma_f32_16x16x32_f16(Ah0, Bl0, acc, 0, 0, 0);
            acc = __builtin_amdgcn_mfma_f32_16x16x32_f16(Ah1, Bl1, acc, 0, 0, 0);
            int jb = jt * 64 + g * 16 + quad * 4;
            float4 xn4 = *(const float4*)&xnb[jb];
            float4 mj4;
            if (MASKED) mj4 = *(const float4*)&smask[jb];
            #pragma unroll
            for (int r = 0; r < 4; ++r) {
                float xnr = (r == 0 ? xn4.x : r == 1 ? xn4.y : r == 2 ? xn4.z : xn4.w);
                float sc = fmaf(mi2, acc[r], -xnr);
                if (MASKED) {
                    float mjr = (r == 0 ? mj4.x : r == 1 ? mj4.y : r == 2 ? mj4.z : mj4.w);
                    sc = (mjr != 0.f) ? sc : 0.0f;
                }
                int bi = __float_as_int(sc);
                unsigned u2 = (unsigned)(bi ^ ((bi >> 31) | 0x80000000));
                int slot = g * 4 + r;
                d[slot] = (u2 & 0xFFFFFFF0u) | (unsigned)(15 - slot);
            }
        }
        #pragma unroll
        for (int p = 1; p < 16; p <<= 1) {
            #pragma unroll
            for (int k = p; k >= 1; k >>= 1) {
                #pragma unroll
                for (int j = k & (p - 1); j + k < 16; j += 2 * k) {
                    #pragma unroll
                    for (int i = 0; i < k; ++i) {
                        if ((i + j + k < 16) &&
                            ((i + j) / (2 * p) == (i + j + k) / (2 * p)))
                            casu(d[i + j], d[i + j + k]);
                    }
                }
            }
        }
        #pragma unroll
        for (int i = 0; i < 10; ++i) {
            unsigned dv = d[15 - i];
            int code = 15 - (int)(dv & 15u);
            int jnew = jt * 64 + (code >> 2) * 16 + quad * 4 + (code & 3);
            bool keep = kv[i] >= dv;
            kj[i] = keep ? kj[i] : jnew;
            kv[i] = keep ? kv[i] : dv;
        }
        cas_kj(kv[0], kj[0], kv[8], kj[8]);
        cas_kj(kv[1], kj[1], kv[9], kj[9]);
        cas_kj(kv[0], kj[0], kv[4], kj[4]);
        cas_kj(kv[1], kj[1], kv[5], kj[5]);
        cas_kj(kv[2], kj[2], kv[6], kj[6]);
        cas_kj(kv[3], kj[3], kv[7], kj[7]);
        cas_kj(kv[0], kj[0], kv[2], kj[2]);
        cas_kj(kv[1], kj[1], kv[3], kj[3]);
        cas_kj(kv[4], kj[4], kv[6], kj[6]);
        cas_kj(kv[5], kj[5], kv[7], kj[7]);
        cas_kj(kv[0], kj[0], kv[1], kj[1]);
        cas_kj(kv[2], kj[2], kv[3], kj[3]);
        cas_kj(kv[4], kj[4], kv[5], kj[5]);
        cas_kj(kv[6], kj[6], kv[7], kj[7]);
        cas_kj(kv[8], kj[8], kv[9], kj[9]);
        if (jt < 7) {                      // write next buffer; prev readers barrier-protected
            jbufH4[1 - cur][tid] = pa0; jbufH4[1 - cur][256 + tid] = pa1;
            jbufL4[1 - cur][tid] = pb0; jbufL4[1 - cur][256 + tid] = pb1;
        }
        __syncthreads();
    }
    #pragma unroll
    for (int qq = 0; qq < 10; ++qq) {
        ldsMV[w][(lane16 * 4 + quad) * 11 + qq] = kv[qq];
        ldsMJ[w][(lane16 * 4 + quad) * 11 + qq] = (unsigned short)kj[qq];
    }
    __syncthreads();
    if (quad == 0) {
        const unsigned* MV = &ldsMV[w][lane16 * 44];
        const unsigned short* MJ = &ldsMJ[w][lane16 * 44];
        int p0 = 9, p1 = 9, p2 = 9, p3 = 9;
        int* op = idx_out + ((size_t)bq * 512 + irow) * 16;
        for (int t = 0; t < K; ++t) {
            unsigned bv = 0u; int bj = 0x7fffffff; int bc = -1;
            { unsigned v = MV[p0]; int j = MJ[p0];
              if (v > bv || (v == bv && j < bj)) { bv = v; bj = j; bc = 0; } }
            { unsigned v = MV[11 + p1]; int j = MJ[11 + p1];
              if (v > bv || (v == bv && j < bj)) { bv = v; bj = j; bc = 1; } }
            { unsigned v = MV[22 + p2]; int j = MJ[22 + p2];
              if (v > bv || (v == bv && j < bj)) { bv = v; bj = j; bc = 2; } }
            { unsigned v = MV[33 + p3]; int j = MJ[33 + p3];
              if (v > bv || (v == bv && j < bj)) { bv = v; bj = j; bc = 3; } }
            if (bc == 0) --p0; else if (bc == 1) --p1; else if (bc == 2) --p2; else --p3;
            op[t] = bj;
        }
    }
}

// ---------------- fused branch (unchanged): grid (96,8) ----------------
template<int ACC>
__global__ void __attribute__((amdgpu_flat_work_group_size(256, 256), amdgpu_waves_per_eu(2, 4)))
fused_branch_kernel(
    const _Float16* __restrict__ H, const _Float16* __restrict__ L,
    const _Float16* __restrict__ WH, const _Float16* __restrict__ WL,
    const int* __restrict__ idx, const float* __restrict__ masks, int remap,
    const float* __restrict__ bias,
    const float* __restrict__ g, const float* __restrict__ bb,
    const float* __restrict__ mm, const float* __restrict__ vv,
    float* __restrict__ out_p, float* __restrict__ vec_out)
{
    __shared__ float ldsA[8 * 512];
    __shared__ float ldsB[8 * 512];
    __shared__ unsigned short ldsIdx[512 * 10];
    __shared__ float smask[512];
    int bq = blockIdx.x, ob = blockIdx.y * 8;
    int row = remap ? src_row(bq) : bq;
    bool use_mask = (masks != nullptr);
    int tid = threadIdx.x, w = tid >> 6, l = tid & 63;
    int lane16 = l & 15, quad = l >> 4;
    const size_t base = (size_t)row * 32768;
    for (int p = 0; p < 20; ++p) {
        int t = p * 256 + tid;
        int i = t / 10, q = t - i * 10;
        ldsIdx[t] = (unsigned short)idx[((size_t)bq * 512 + i) * 16 + q];
    }
    if (use_mask) {
        smask[tid] = masks[bq * 512 + tid];
        smask[tid + 256] = masks[bq * 512 + tid + 256];
    }
    __syncthreads();
    {
        int wrow = (lane16 < 8) ? (ob + lane16) : (64 + ob + (lane16 - 8));
        size_t woff = (size_t)wrow * 64 + quad * 8;
        half8 Ah0 = *(const half8*)(WH + woff);
        half8 Ah1 = *(const half8*)(WH + woff + 32);
        half8 Al0 = *(const half8*)(WL + woff);
        half8 Al1 = *(const half8*)(WL + woff + 32);
        float* dst = (quad < 2) ? (ldsA + (quad * 4) * 512) : (ldsB + ((quad - 2) * 4) * 512);
        for (int k = 0; k < 8; ++k) {
            int it = w * 8 + k;
            size_t off = base + (((size_t)(it >> 2) * 8 + quad) * 64 + (it & 3) * 16 + lane16) * 8;
            half8 Xh0 = *(const half8*)(H + off);
            half8 Xh1 = *(const half8*)(H + off + 2048);
            half8 Xl0 = *(const half8*)(L + off);
            half8 Xl1 = *(const half8*)(L + off + 2048);
            if (use_mask) {
                float m = smask[it * 16 + lane16];
                if (m == 0.f) {
                    half8 z = {};
                    Xh0 = z; Xh1 = z; Xl0 = z; Xl1 = z;
                }
            }
            f32x4 acc = {0.f, 0.f, 0.f, 0.f};
            acc = __builtin_amdgcn_mfma_f32_16x16x32_f16(Ah0, Xh0, acc, 0, 0, 0);
            acc = __builtin_amdgcn_mfma_f32_16x16x32_f16(Ah1, Xh1, acc, 0, 0, 0);
            acc = __builtin_amdgcn_mfma_f32_16x16x32_f16(Ah0, Xl0, acc, 0, 0, 0);
            acc = __builtin_amdgcn_mfma_f32_16x16x32_f16(Ah1, Xl1, acc, 0, 0, 0);
            acc = __builtin_amdgcn_mfma_f32_16x16x32_f16(Al0, Xh0, acc, 0, 0, 0);
            acc = __builtin_amdgcn_mfma_f32_16x16x32_f16(Al1, Xh1, acc, 0, 0, 0);
            #pragma unroll
            for (int r = 0; r < 4; ++r)
                dst[r * 512 + it * 16 + lane16] = acc[r];
        }
    }
    __syncthreads();
    float ssr[2], str[2];
    #pragma unroll
    for (int oo = 0; oo < 2; ++oo) {
        int o = ob + w * 2 + oo;
        float sc = g[o] / sqrtf(vv[o] + EPS);
        ssr[oo] = sc;
        str[oo] = bb[o] - mm[o] * sc + bias[bq * 64 + o] * sc;
    }
    float omax[2], osum[2];
    #pragma unroll
    for (int oo = 0; oo < 2; ++oo) { omax[oo] = -3.4e38f; osum[oo] = 0.f; }
    const float* Aw = ldsA + (w * 2) * 512;
    const float* Bw = ldsB + (w * 2) * 512;
    for (int s = 0; s < 8; ++s) {
        int i = l + 64 * s;
        int idr[10];
        const unsigned short* ip = &ldsIdx[i * 10];
        #pragma unroll
        for (int q = 0; q < 10; ++q) idr[q] = ip[q];
        #pragma unroll
        for (int oo = 0; oo < 2; ++oo) {
            const float* Ao = Aw + oo * 512;
            float mx = Ao[idr[0]];
            #pragma unroll
            for (int q = 1; q < 10; ++q) mx = fmaxf(mx, Ao[idr[q]]);
            float val = (mx + Bw[oo * 512 + i]) * ssr[oo] + str[oo];
            float y = val > 0.f ? val : 0.2f * val;
            omax[oo] = fmaxf(omax[oo], y);
            osum[oo] += y;
        }
    }
    #pragma unroll
    for (int oo = 0; oo < 2; ++oo) {
        float M = omax[oo], S = osum[oo];
        #pragma unroll
        for (int off = 32; off >= 1; off >>= 1) {
            M = fmaxf(M, __shfl_down(M, off));
            S += __shfl_down(S, off);
        }
        if (l == 0) {
            int o = ob + w * 2 + oo;
            float* po = out_p + bq * 128;
            if (ACC) {
                po[o] += M;
                po[64 + o] += S * (1.f / 512.f);
            } else {
                po[o] = M;
                po[64 + o] = S * (1.f / 512.f);
                vec_out[bq * 64 + o] = M;
            }
        }
    }
}

extern "C" void kernel_launch(void* const* d_in, const int* in_sizes, int n_in,
                              void* d_out, int out_size, void* d_ws, size_t ws_size,
                              hipStream_t stream)
{
    const float* x        = (const float*)d_in[0];
    const float* w_reduce = (const float*)d_in[1];
    const float* w_erase  = (const float*)d_in[2];
    const float* b_erase  = (const float*)d_in[3];
    const float* g_erase  = (const float*)d_in[4];
    const float* be_erase = (const float*)d_in[5];
    const float* m_erase  = (const float*)d_in[6];
    const float* v_erase  = (const float*)d_in[7];
    const float* w0 = (const float*)d_in[8];
    const float* g0 = (const float*)d_in[9];
    const float* b0 = (const float*)d_in[10];
    const float* m0 = (const float*)d_in[11];
    const float* v0 = (const float*)d_in[12];
    const float* w1 = (const float*)d_in[13];
    const float* g1 = (const float*)d_in[14];
    const float* b1 = (const float*)d_in[15];
    const float* m1 = (const float*)d_in[16];
    const float* v1 = (const float*)d_in[17];
    float* out = (float*)d_out;
    char* ws = (char*)d_ws;

    _Float16* h0 = (_Float16*)(ws);              // 6.29 MB  split of raw x
    _Float16* l0 = (_Float16*)(ws + 6291456);    // 6.29 MB
    int*   idxA  = (int*)(ws + 12582912);        // 3.15 MB
    int*   idxB  = (int*)(ws + 15728640);        // 3.15 MB
    float* xn0   = (float*)(ws + 18874368);      // 192 KB
    float* bias0 = (float*)(ws + 19070976);      // 24 KB
    float* bias1 = (float*)(ws + 19095552);      // 24 KB
    float* x0vec = (float*)(ws + 19120128);      // 24 KB
    float* masks = (float*)(ws + 19144704);      // 192 KB
    _Float16* wh0 = (_Float16*)(ws + 19341312);  // 16 KB
    _Float16* wl0 = (_Float16*)(ws + 19357696);  // 16 KB
    _Float16* wh1 = (_Float16*)(ws + 19374080);  // 16 KB
    _Float16* wl1 = (_Float16*)(ws + 19390464);  // 16 KB

    (void)in_sizes; (void)n_in; (void)out_size; (void)ws_size;

    // 1. prep (768) + erase0 (96)
    prep_kernel<<<864, 256, 0, stream>>>(x, h0, l0, xn0, w0, w1, wh0, wl0, wh1, wl1,
                                         w_erase, b_erase, g_erase, be_erase, m_erase, v_erase, bias0);
    // 2. kNN on x (translation-invariant: same as kNN on x0)
    knn_kernel<0><<<768, 256, 0, stream>>>(h0, l0, xn0, idxA, 10,
                                           nullptr, nullptr, nullptr, nullptr,
                                           nullptr, nullptr, nullptr, nullptr, nullptr, nullptr,
                                           nullptr, nullptr, nullptr);
    // 3. branch 0
    fused_branch_kernel<0><<<dim3(96, 8), 256, 0, stream>>>(h0, l0, wh0, wl0, idxA, nullptr, 0, bias0,
                                                            g0, b0, m0, v0, out, x0vec);
    // 4. corre + erase1 + masked kNN fused (itile0 publishes masks/bias1)
    knn_kernel<1><<<768, 256, 0, stream>>>(h0, l0, xn0, idxB, 10,
                                           x, x0vec, w_reduce, idxA,
                                           w_erase, b_erase, g_erase, be_erase, m_erase, v_erase,
                                           w1, masks, bias1);
    // 5. branch 1
    fused_branch_kernel<1><<<dim3(96, 8), 256, 0, stream>>>(h0, l0, wh1, wl1, idxB, masks, 1, bias1,
                                                            g1, b1, m1, v1, out, nullptr);
}